// Round 7
// baseline (1218.182 us; speedup 1.0000x reference)
//
#include <hip/hip_runtime.h>
#include <stdint.h>
#include <stddef.h>

// Inputs/outputs fp32 (established R1-R4). X is converted to bf16 once in ws;
// all GEMMs are bf16-MFMA with fp32 accumulate, register-staged LDS tiles
// (R5's 2.2 TB/s structure), stride-72 padded LDS (R5: conflict-free reads),
// LDS-tiled coalesced bf16 epilogue (R6: WRITE 280->131 MB).

using u16 = unsigned short;
using u32 = unsigned int;

__device__ __forceinline__ float u2f(u16 u) {
  union { unsigned i; float f; } c; c.i = ((unsigned)u) << 16; return c.f;
}
__device__ __forceinline__ u16 f2u(float f) {
  union { float f; unsigned i; } c; c.f = f;
  unsigned u = c.i;
  u += 0x7fffu + ((u >> 16) & 1u);   // RNE to bf16
  return (u16)(u >> 16);
}
__device__ __forceinline__ u32 pk2(float lo, float hi) {
  return (u32)f2u(lo) | ((u32)f2u(hi) << 16);
}
__device__ __forceinline__ float sigm(float x) { return 1.f / (1.f + expf(-x)); }

typedef __attribute__((ext_vector_type(8))) short bfrag;   // 8 bf16 = 4 VGPRs
typedef __attribute__((ext_vector_type(4))) float f32x4;

#define LDS_STRIDE 72   // 144 B = 9*16B: b128-aligned, conflict-free frag reads

// fp32 -> bf16, scalar (weights)
__global__ void cvt_kernel(const float* __restrict__ src, u16* __restrict__ dst, int n) {
  int i = blockIdx.x * 256 + threadIdx.x;
  if (i < n) dst[i] = f2u(src[i]);
}

// fp32 -> bf16, vectorized x8 (X: 33554432 elems, grid 16384)
__global__ __launch_bounds__(256)
void cvtx_kernel(const float* __restrict__ src, u16* __restrict__ dst) {
  size_t i = ((size_t)blockIdx.x * 256 + threadIdx.x) * 8;
  float4 f0 = *(const float4*)(src + i);
  float4 f1 = *(const float4*)(src + i + 4);
  uint4 o;
  o.x = pk2(f0.x, f0.y); o.y = pk2(f0.z, f0.w);
  o.z = pk2(f1.x, f1.y); o.w = pk2(f1.z, f1.w);
  *(uint4*)(dst + i) = o;
}

// C = epilogue(A @ W^T). A:[rows,K] bf16 row-major lda. W:[cols,K] bf16 ldw.
// rows%128==0, cols%128==0, K%64==0.
// MODE 0: outb = bf16(relu(acc + ubuf[(b*64+w)*512 + col]))   (ubuf holds bm)
// MODE 1: outb = bf16(relu(acc + bias[col]))
// MODE 2: atomicAdd(pred[row], sum_col relu(acc + bias[col]) * wlo[col])
// MODE 3: outf = acc + bias[col]      (fp32 out, direct stores)
// MODE 4: outb = bf16(relu(sigm(pred[row]) * acc + bias[col]))
template <int MODE>
__global__ __launch_bounds__(256)
void gemm_bt(const u16* __restrict__ A, int lda,
             const u16* __restrict__ W, int ldw, int K,
             const u16* __restrict__ bias,
             const float* __restrict__ ubuf,
             const u16* __restrict__ wlo,
             float* __restrict__ pred,
             u16* __restrict__ outb,
             float* __restrict__ outf,
             int ldc)
{
  __shared__ u16 smem[2 * 128 * LDS_STRIDE];   // 36864 B -> 4 blocks/CU by LDS
  u16* As = smem;
  u16* Bs = smem + 128 * LDS_STRIDE;

  const int tid  = threadIdx.x;
  const int wave = tid >> 6, lane = tid & 63;
  const int wr = wave >> 1, wc = wave & 1;
  const int quad = lane >> 4, l16 = lane & 15;
  const int row0 = blockIdx.y * 128;
  const int col0 = blockIdx.x * 128;
  const int sr = (tid * 4) >> 3;              // base staging row for this thread... (per-i below)

  f32x4 acc[4][4];
#pragma unroll
  for (int i = 0; i < 4; i++)
#pragma unroll
    for (int j = 0; j < 4; j++)
#pragma unroll
      for (int r = 0; r < 4; r++) acc[i][j][r] = 0.f;
  (void)sr;

  uint4 ra[4], rb[4];
#pragma unroll
  for (int i = 0; i < 4; i++) {                // preload k0 = 0
    const int idx = i * 256 + tid, r = idx >> 3, c = (idx & 7) * 8;
    ra[i] = *(const uint4*)(A + (size_t)(row0 + r) * lda + c);
    rb[i] = *(const uint4*)(W + (size_t)(col0 + r) * ldw + c);
  }

  for (int k0 = 0; k0 < K; k0 += 64) {
    __syncthreads();                           // prior tile's LDS reads done
#pragma unroll
    for (int i = 0; i < 4; i++) {
      const int idx = i * 256 + tid, r = idx >> 3, c = (idx & 7) * 8;
      *(uint4*)(As + r * LDS_STRIDE + c) = ra[i];   // vmcnt wait lands here
      *(uint4*)(Bs + r * LDS_STRIDE + c) = rb[i];
    }
    __syncthreads();
    if (k0 + 64 < K) {                         // issue next tile's loads now;
#pragma unroll                                 // they overlap MFMA + next barrier
      for (int i = 0; i < 4; i++) {
        const int idx = i * 256 + tid, r = idx >> 3, c = (idx & 7) * 8;
        ra[i] = *(const uint4*)(A + (size_t)(row0 + r) * lda + (k0 + 64) + c);
        rb[i] = *(const uint4*)(W + (size_t)(col0 + r) * ldw + (k0 + 64) + c);
      }
    }
#pragma unroll
    for (int kk = 0; kk < 64; kk += 32) {
      bfrag af[4], bf[4];
#pragma unroll
      for (int mt = 0; mt < 4; mt++)
        af[mt] = *(const bfrag*)(As + (wr * 64 + mt * 16 + l16) * LDS_STRIDE + kk + quad * 8);
#pragma unroll
      for (int nt = 0; nt < 4; nt++)
        bf[nt] = *(const bfrag*)(Bs + (wc * 64 + nt * 16 + l16) * LDS_STRIDE + kk + quad * 8);
#pragma unroll
      for (int mt = 0; mt < 4; mt++)
#pragma unroll
        for (int nt = 0; nt < 4; nt++)
          acc[mt][nt] = __builtin_amdgcn_mfma_f32_16x16x32_bf16(af[mt], bf[nt], acc[mt][nt], 0, 0, 0);
    }
  }

  // C/D layout (verified m89/m91): col = lane&15, row = quad*4 + reg
  if constexpr (MODE == 2) {
#pragma unroll
    for (int mt = 0; mt < 4; mt++) {
#pragma unroll
      for (int r = 0; r < 4; r++) {
        const int rg = row0 + wr * 64 + mt * 16 + quad * 4 + r;
        float s = 0.f;
#pragma unroll
        for (int nt = 0; nt < 4; nt++) {
          const int cg = col0 + wc * 64 + nt * 16 + l16;
          float v = acc[mt][nt][r] + u2f(bias[cg]);
          v = fmaxf(v, 0.f);
          s += v * u2f(wlo[cg]);
        }
#pragma unroll
        for (int off = 1; off < 16; off <<= 1) s += __shfl_xor(s, off, 16);
        if (l16 == 0) atomicAdd(pred + rg, s);
      }
    }
  } else if constexpr (MODE == 3) {
#pragma unroll
    for (int mt = 0; mt < 4; mt++)
#pragma unroll
      for (int nt = 0; nt < 4; nt++)
#pragma unroll
        for (int r = 0; r < 4; r++) {
          const int rg = row0 + wr * 64 + mt * 16 + quad * 4 + r;
          const int cg = col0 + wc * 64 + nt * 16 + l16;
          outf[(size_t)rg * ldc + cg] = acc[mt][nt][r] + u2f(bias[cg]);
        }
  } else {
    // bf16 epilogue through LDS tile (128 x 136) for coalesced 16B stores
    u16* tile = smem;
    __syncthreads();                           // all waves done with As/Bs
#pragma unroll
    for (int mt = 0; mt < 4; mt++)
#pragma unroll
      for (int nt = 0; nt < 4; nt++)
#pragma unroll
        for (int r = 0; r < 4; r++) {
          const int lrow = wr * 64 + mt * 16 + quad * 4 + r;
          const int lcol = wc * 64 + nt * 16 + l16;
          const int rg = row0 + lrow;
          const int cg = col0 + lcol;
          float v = acc[mt][nt][r];
          if constexpr (MODE == 0) {
            const int urow = ((rg >> 12) << 6) | (rg & 63);   // b*64 + w
            v += ubuf[(size_t)urow * 512 + cg];
            v = fmaxf(v, 0.f);
          } else if constexpr (MODE == 1) {
            v += u2f(bias[cg]);
            v = fmaxf(v, 0.f);
          } else {  // MODE 4
            v = sigm(pred[rg]) * v + u2f(bias[cg]);
            v = fmaxf(v, 0.f);
          }
          tile[lrow * 136 + lcol] = f2u(v);
        }
    __syncthreads();
    const int row = tid >> 1, half = tid & 1;
    const u16* src = tile + row * 136 + half * 64;
    u16* dst = outb + (size_t)(row0 + row) * ldc + col0 + half * 64;
#pragma unroll
    for (int j = 0; j < 8; j++)
      *(uint4*)(dst + j * 8) = *(const uint4*)(src + j * 8);
  }
}

__global__ void fill_kernel(float* __restrict__ p, const u16* __restrict__ val, int n) {
  int i = blockIdx.x * blockDim.x + threadIdx.x;
  if (i < n) p[i] = u2f(*val);
}

__global__ void adj_out_kernel(const float* __restrict__ r, float* __restrict__ out) {
  int i = blockIdx.x * 256 + threadIdx.x;            // (b,v,w)
  int b = i >> 12, v = (i >> 6) & 63, w = i & 63;
  out[i] = r[(b << 12) + (w << 6) + v];              // pred_adj[b,v,w] = r[b,w,v]
}

__global__ __launch_bounds__(512)
void msum_kernel(const float* __restrict__ r, const u16* __restrict__ M, u16* __restrict__ x) {
  const int bv = blockIdx.x;                          // b*64+v
  const int b = bv >> 6, v = bv & 63;
  __shared__ float s[64];
  if (threadIdx.x < 64) {
    const int w = threadIdx.x;
    s[w] = sigm(r[(b << 12) + (w << 6) + v]);
  }
  __syncthreads();
  const int m = threadIdx.x;                          // channel 0..511
  const u16* Mp = M + (((size_t)(b << 12) + (v << 6)) << 9) + m;
  float acc = 0.f;
#pragma unroll 8
  for (int w = 0; w < 64; w++) acc += s[w] * u2f(Mp[(size_t)w << 9]);
  x[(size_t)bv * 512 + m] = f2u(acc);
}

__global__ __launch_bounds__(256)
void gru_kernel(const float* __restrict__ gi, const float* __restrict__ gh,
                const u16* __restrict__ h, float* __restrict__ hn) {
  int i = blockIdx.x * 256 + threadIdx.x;             // 1024*512
  int row = i >> 9, d = i & 511;
  const float* gir = gi + (size_t)row * 1536;
  const float* ghr = gh + (size_t)row * 1536;
  float rr = sigm(gir[d] + ghr[d]);
  float z  = sigm(gir[512 + d] + ghr[512 + d]);
  float n  = tanhf(gir[1024 + d] + rr * ghr[1024 + d]);
  float hv = u2f(h[i]);
  hn[i] = (1.f - z) * n + z * hv;
}

__global__ __launch_bounds__(256)
void readout_kernel(const float* __restrict__ hn,
                    const u16* __restrict__ Wr1, const u16* __restrict__ br1,
                    const u16* __restrict__ Wr2, const u16* __restrict__ br2,
                    float* __restrict__ out) {
  const int row = blockIdx.x;
  __shared__ float hrow[512];
  for (int d = threadIdx.x; d < 512; d += 256) hrow[d] = hn[(size_t)row * 512 + d];
  __syncthreads();
  const int wave = threadIdx.x >> 6, lane = threadIdx.x & 63;
  for (int j = wave; j < 28; j += 4) {   // 4 waves, stride 4 (R3 fix)
    const u16* wrow;
    float bias;
    size_t off;
    if (j < 26) { wrow = Wr1 + (size_t)j * 512; bias = u2f(br1[j]); off = 65536 + (size_t)row * 26 + j; }
    else { int jj = j - 26; wrow = Wr2 + (size_t)jj * 512; bias = u2f(br2[jj]); off = 92160 + (size_t)row * 2 + jj; }
    float s = 0.f;
    for (int d = lane; d < 512; d += 64) s += hrow[d] * u2f(wrow[d]);
#pragma unroll
    for (int o = 32; o; o >>= 1) s += __shfl_down(s, o);
    if (lane == 0) out[off] = s + bias;
  }
}

extern "C" void kernel_launch(void* const* d_in, const int* in_sizes, int n_in,
                              void* d_out, int out_size, void* d_ws, size_t ws_size,
                              hipStream_t stream)
{
  (void)in_sizes; (void)n_in; (void)out_size; (void)ws_size;
  const float* X = (const float*)d_in[0];     // [16,64,64,512] fp32
  char* ws = (char*)d_ws;

  // Two aliased 64 MB slots (liveness-ordered):
  //   slotA: Xb (bf16 X)  ->  H1' (gated link hidden)
  //   slotB: H1 (link1)   ->  Mb  (message M)
  u16*   slotA = (u16*)(ws);
  u16*   slotB = (u16*)(ws + 67108864);
  float* pred1 = (float*)(ws + 134217728);    // 256 KB
  float* rbuf  = (float*)(ws + 134479872);    // 256 KB
  float* ubuf  = (float*)(ws + 134742016);    // 2 MB  u = nf@Wm_h^T + bm (fp32)
  u16*   xbuf  = (u16*)(ws + 136839168);      // 1 MB  GRU input bf16
  float* gi    = (float*)(ws + 137887744);    // 6 MB
  float* gh    = (float*)(ws + 144179200);    // 6 MB
  float* hn    = (float*)(ws + 150470656);    // 2 MB
  u16*   nfb   = (u16*)(ws + 152567808);
  u16*   Wmb   = (u16*)(ws + 153616384);
  u16*   bmb   = (u16*)(ws + 154664960);
  u16*   Wl1b  = (u16*)(ws + 154665984);
  u16*   bl1b  = (u16*)(ws + 155190272);
  u16*   Wl2b  = (u16*)(ws + 155191296);
  u16*   bl2b  = (u16*)(ws + 155715584);
  u16*   Wlob  = (u16*)(ws + 155716608);
  u16*   blob  = (u16*)(ws + 155717632);
  u16*   Wihb  = (u16*)(ws + 155718656);
  u16*   bihb  = (u16*)(ws + 157291520);
  u16*   Whhb  = (u16*)(ws + 157295616);
  u16*   bhhb  = (u16*)(ws + 158868480);
  u16*   Wr1b  = (u16*)(ws + 158872576);
  u16*   br1b  = (u16*)(ws + 158901248);
  u16*   Wr2b  = (u16*)(ws + 158902272);
  u16*   br2b  = (u16*)(ws + 158904320);
  // total: 158,905,344 B (same budget as R6 big path, proven to fit)

  float* out = (float*)d_out;

  // X -> bf16 (read once as fp32)
  cvtx_kernel<<<16384, 256, 0, stream>>>(X, slotA);

#define CVT(idx, dst, n) cvt_kernel<<<((n) + 255) / 256, 256, 0, stream>>>((const float*)d_in[idx], dst, n)
  CVT(1,  nfb,  524288);
  CVT(4,  Wmb,  524288);
  CVT(5,  bmb,  512);
  CVT(6,  Wl1b, 262144);
  CVT(7,  bl1b, 512);
  CVT(8,  Wl2b, 262144);
  CVT(9,  bl2b, 512);
  CVT(10, Wlob, 512);
  CVT(11, blob, 1);
  CVT(12, Wihb, 786432);
  CVT(13, bihb, 1536);
  CVT(14, Whhb, 786432);
  CVT(15, bhhb, 1536);
  CVT(16, Wr1b, 13312);
  CVT(17, br1b, 26);
  CVT(18, Wr2b, 1024);
  CVT(19, br2b, 2);
#undef CVT

  // u = nf @ Wm[:, :512]^T + bm  (fp32)
  gemm_bt<3><<<dim3(4, 8), 256, 0, stream>>>(nfb, 512, Wmb, 1024, 512, bmb,
      nullptr, nullptr, nullptr, nullptr, ubuf, 512);
  // pred1 & rbuf (contiguous 131072 floats) = blo
  fill_kernel<<<512, 256, 0, stream>>>(pred1, blob, 131072);

  // link round 1: H1(slotB) = relu(Xb @ Wl1^T + bl1)
  gemm_bt<1><<<dim3(4, 512), 256, 0, stream>>>(slotA, 512, Wl1b, 512, 512, bl1b,
      nullptr, nullptr, nullptr, slotB, nullptr, 512);
  // pred1 += sum relu(H1 @ Wl2^T + bl2) * Wlo
  gemm_bt<2><<<dim3(4, 512), 256, 0, stream>>>(slotB, 512, Wl2b, 512, 512, bl2b,
      nullptr, Wlob, pred1, nullptr, nullptr, 512);
  // M(slotB, overwrites dead H1) = relu(Xb @ Wm_e^T + u)
  gemm_bt<0><<<dim3(4, 512), 256, 0, stream>>>(slotA, 512, Wmb + 512, 1024, 512,
      nullptr, ubuf, nullptr, nullptr, slotB, nullptr, 512);
  // gated link 1: H1'(slotA, overwrites dead Xb) = relu(sigm(pred1)*(M@Wl1^T) + bl1)
  gemm_bt<4><<<dim3(4, 512), 256, 0, stream>>>(slotB, 512, Wl1b, 512, 512, bl1b,
      nullptr, nullptr, pred1, slotA, nullptr, 512);
  // rbuf += sum relu(H1' @ Wl2^T + bl2) * Wlo
  gemm_bt<2><<<dim3(4, 512), 256, 0, stream>>>(slotA, 512, Wl2b, 512, 512, bl2b,
      nullptr, Wlob, rbuf, nullptr, nullptr, 512);

  // pred_adj[b,v,w] = rbuf[b,w,v]
  adj_out_kernel<<<256, 256, 0, stream>>>(rbuf, out);
  // x[b,v,:] = sum_w sigm(rbuf[b,w,v]) * M[b,:,v,w]
  msum_kernel<<<1024, 512, 0, stream>>>(rbuf, slotB, xbuf);
  // GRU gates
  gemm_bt<3><<<dim3(12, 8), 256, 0, stream>>>(xbuf, 512, Wihb, 512, 512, bihb,
      nullptr, nullptr, nullptr, nullptr, gi, 1536);
  gemm_bt<3><<<dim3(12, 8), 256, 0, stream>>>(nfb, 512, Whhb, 512, 512, bhhb,
      nullptr, nullptr, nullptr, nullptr, gh, 1536);
  gru_kernel<<<2048, 256, 0, stream>>>(gi, gh, nfb, hn);
  readout_kernel<<<1024, 256, 0, stream>>>(hn, Wr1b, br1b, Wr2b, br2b, out);
}